// Round 1
// baseline (82.277 us; speedup 1.0000x reference)
//
#include <hip/hip_runtime.h>

#define NUM_ATOMS 3
#define MAX_NODES 15
#define VPT 8           // elements (j values) per thread
#define EPS_K 1e-6f

// General post-order stack-machine tree evaluator.
// Atoms: 0=rbf, 1=linear, 2=periodic ; operators: 3=add, >=4=mul
// (matches ref: is_operator[clip(v,0,4)] == (v >= NUM_ATOMS) for the given
//  library, and the clip() semantics of lax.switch).
__global__ __launch_bounds__(256) void tree_eval_kernel(
    const float* __restrict__ x, const float* __restrict__ y,
    const int* __restrict__ expr, const int* __restrict__ lvl,
    const float* __restrict__ params, float* __restrict__ out, int d2)
{
    __shared__ int   s_expr[MAX_NODES];
    __shared__ int   s_lvl[MAX_NODES];
    __shared__ float s_par[MAX_NODES][3];
    if (threadIdx.x < MAX_NODES) {
        const int t = threadIdx.x;
        s_expr[t]   = expr[t];
        s_lvl[t]    = lvl[t];
        s_par[t][0] = params[3 * t + 0];
        s_par[t][1] = params[3 * t + 1];
        s_par[t][2] = params[3 * t + 2];
    }
    __syncthreads();

    const int   i  = blockIdx.x;
    const int   jb = threadIdx.x * VPT;
    const float xi = x[i];

    float yv[VPT];
    {
        const float4* y4 = reinterpret_cast<const float4*>(y + jb);
        float4 a = y4[0], b = y4[1];
        yv[0] = a.x; yv[1] = a.y; yv[2] = a.z; yv[3] = a.w;
        yv[4] = b.x; yv[5] = b.y; yv[6] = b.z; yv[7] = b.w;
    }

    // 4-deep stack held in registers (explicit switch on ptr; ptr is
    // wave-uniform in practice so branches don't diverge).
    float s0[VPT], s1[VPT], s2[VPT], s3[VPT];
#pragma unroll
    for (int k = 0; k < VPT; ++k) { s0[k] = 0.f; s1[k] = 0.f; s2[k] = 0.f; s3[k] = 0.f; }

    float tmp[VPT];
    int ptr = 0;

    for (int n = 0; n < MAX_NODES; ++n) {
        const int v = s_expr[n];
        if (v < 0) continue;

        if (v >= NUM_ATOMS) {
            // operator: l = stack[ptr-1], r = stack[ptr-2] -> stack[ptr-2]
            const bool isAdd = (v == NUM_ATOMS);  // clip(v-3,0,1): 3->add, >=4->mul
            switch (ptr) {
                case 2:
#pragma unroll
                    for (int k = 0; k < VPT; ++k)
                        s0[k] = isAdd ? (s1[k] + s0[k]) : (s1[k] * s0[k]);
                    break;
                case 3:
#pragma unroll
                    for (int k = 0; k < VPT; ++k)
                        s1[k] = isAdd ? (s2[k] + s1[k]) : (s2[k] * s1[k]);
                    break;
                default:
#pragma unroll
                    for (int k = 0; k < VPT; ++k)
                        s2[k] = isAdd ? (s3[k] + s2[k]) : (s3[k] * s2[k]);
                    break;
            }
            ptr -= 1;
        } else {
            // leaf atom using parameters[lvl[n]]
            const int   L  = s_lvl[n];
            const float p0 = s_par[L][0], p1 = s_par[L][1], p2 = s_par[L][2];
            const float p0sq = p0 * p0;

            if (v == 0) {                       // rbf
                const float rinv = __fdividef(0.5f, p1 * p1 + EPS_K);
#pragma unroll
                for (int k = 0; k < VPT; ++k) {
                    const float dx = xi - yv[k];
                    tmp[k] = p0sq * __expf(-dx * dx * rinv);
                }
            } else if (v == 1) {                // linear
                const float p1sq = p1 * p1;
#pragma unroll
                for (int k = 0; k < VPT; ++k)
                    tmp[k] = p0sq * (xi * yv[k]) + p1sq;
            } else {                            // periodic (v>=2 clipped to 2)
                const float invp = __fdividef(1.0f, p2 * p2 + 1.0f);
                const float rinv = __fdividef(2.0f, p1 * p1 + EPS_K);
#pragma unroll
                for (int k = 0; k < VPT; ++k) {
                    const float s = sinpif((xi - yv[k]) * invp);
                    tmp[k] = p0sq * __expf(-s * s * rinv);
                }
            }

            switch (ptr) {
                case 0:
#pragma unroll
                    for (int k = 0; k < VPT; ++k) s0[k] = tmp[k];
                    break;
                case 1:
#pragma unroll
                    for (int k = 0; k < VPT; ++k) s1[k] = tmp[k];
                    break;
                case 2:
#pragma unroll
                    for (int k = 0; k < VPT; ++k) s2[k] = tmp[k];
                    break;
                default:
#pragma unroll
                    for (int k = 0; k < VPT; ++k) s3[k] = tmp[k];
                    break;
            }
            ptr += 1;
        }
    }

    // result = stack[0]
    float4 o0 = make_float4(s0[0], s0[1], s0[2], s0[3]);
    float4 o1 = make_float4(s0[4], s0[5], s0[6], s0[7]);
    float4* o4 = reinterpret_cast<float4*>(out + (size_t)i * d2 + jb);
    o4[0] = o0;
    o4[1] = o1;
}

extern "C" void kernel_launch(void* const* d_in, const int* in_sizes, int n_in,
                              void* d_out, int out_size, void* d_ws, size_t ws_size,
                              hipStream_t stream) {
    const float* x      = (const float*)d_in[0];
    const float* y      = (const float*)d_in[1];
    const int*   expr   = (const int*)d_in[2];
    const int*   lvl    = (const int*)d_in[3];
    // d_in[4] = is_operator: library-fixed ([F,F,F,T,T]); encoded as v>=NUM_ATOMS.
    const float* params = (const float*)d_in[5];
    float*       out    = (float*)d_out;

    const int d1 = in_sizes[0];
    const int d2 = in_sizes[1];

    dim3 grid(d1);
    dim3 block(d2 / VPT);   // 2048/8 = 256
    tree_eval_kernel<<<grid, block, 0, stream>>>(x, y, expr, lvl, params, out, d2);
}

// Round 2
// 78.582 us; speedup vs baseline: 1.0470x; 1.0470x over previous
//
#include <hip/hip_runtime.h>

#define NUM_ATOMS 3
#define MAX_NODES 15
#define VPT 8           // elements (j values) per thread
#define EPS_K 1e-6f
#define LOG2E 1.4426950408889634f

__device__ __forceinline__ float fexp2(float a) {
#if __has_builtin(__builtin_amdgcn_exp2f)
    return __builtin_amdgcn_exp2f(a);     // v_exp_f32: D = 2^S0
#else
    return exp2f(a);
#endif
}
// sin(2*pi*a) — hardware v_sin_f32 takes REVOLUTIONS. Valid for |a| up to
// hundreds of revs; here |a| <= ~4.
__device__ __forceinline__ float fsin_rev(float a) {
#if __has_builtin(__builtin_amdgcn_sinf)
    return __builtin_amdgcn_sinf(a);
#else
    return __sinf(a * 6.283185307179586f);
#endif
}

// General post-order stack-machine tree evaluator.
// Atoms: 0=rbf, 1=linear, 2=periodic ; operators: 3=add, >=4=mul
__global__ __launch_bounds__(256) void tree_eval_kernel(
    const float* __restrict__ x, const float* __restrict__ y,
    const int* __restrict__ expr, const int* __restrict__ lvl,
    const float* __restrict__ params, float* __restrict__ out, int d2)
{
    __shared__ int   s_expr[MAX_NODES];
    __shared__ int   s_lvl[MAX_NODES];
    __shared__ float s_par[MAX_NODES][3];
    if (threadIdx.x < MAX_NODES) {
        const int t = threadIdx.x;
        s_expr[t]   = expr[t];
        s_lvl[t]    = lvl[t];
        s_par[t][0] = params[3 * t + 0];
        s_par[t][1] = params[3 * t + 1];
        s_par[t][2] = params[3 * t + 2];
    }
    __syncthreads();

    const int   i  = blockIdx.x;
    const int   jb = threadIdx.x * VPT;
    const float xi = x[i];

    float yv[VPT];
    {
        const float4* y4 = reinterpret_cast<const float4*>(y + jb);
        float4 a = y4[0], b = y4[1];
        yv[0] = a.x; yv[1] = a.y; yv[2] = a.z; yv[3] = a.w;
        yv[4] = b.x; yv[5] = b.y; yv[6] = b.z; yv[7] = b.w;
    }

    // 4-deep stack held in registers (ptr is uniform -> no divergence).
    float s0[VPT], s1[VPT], s2[VPT], s3[VPT];
#pragma unroll
    for (int k = 0; k < VPT; ++k) { s0[k] = 0.f; s1[k] = 0.f; s2[k] = 0.f; s3[k] = 0.f; }

    float tmp[VPT];
    int ptr = 0;

    for (int n = 0; n < MAX_NODES; ++n) {
        const int v = s_expr[n];
        if (v < 0) continue;

        if (v >= NUM_ATOMS) {
            const bool isAdd = (v == NUM_ATOMS);
            switch (ptr) {
                case 2:
#pragma unroll
                    for (int k = 0; k < VPT; ++k)
                        s0[k] = isAdd ? (s1[k] + s0[k]) : (s1[k] * s0[k]);
                    break;
                case 3:
#pragma unroll
                    for (int k = 0; k < VPT; ++k)
                        s1[k] = isAdd ? (s2[k] + s1[k]) : (s2[k] * s1[k]);
                    break;
                default:
#pragma unroll
                    for (int k = 0; k < VPT; ++k)
                        s2[k] = isAdd ? (s3[k] + s2[k]) : (s3[k] * s2[k]);
                    break;
            }
            ptr -= 1;
        } else {
            const int   L  = s_lvl[n];
            const float p0 = s_par[L][0], p1 = s_par[L][1], p2 = s_par[L][2];
            const float p0sq = p0 * p0;

            if (v == 0) {                       // rbf: p0^2 * 2^(dx^2 * c1)
                const float c1 = -0.5f * LOG2E / (p1 * p1 + EPS_K);
#pragma unroll
                for (int k = 0; k < VPT; ++k) {
                    const float dx = xi - yv[k];
                    tmp[k] = p0sq * fexp2(dx * dx * c1);
                }
            } else if (v == 1) {                // linear: fma(p0^2*xi, yv, p1^2)
                const float a    = p0sq * xi;   // block-uniform
                const float p1sq = p1 * p1;
#pragma unroll
                for (int k = 0; k < VPT; ++k)
                    tmp[k] = fmaf(a, yv[k], p1sq);
            } else {                            // periodic
                const float inv2p = 0.5f / (p2 * p2 + 1.0f);   // rev per dx
                const float c2    = -2.0f * LOG2E / (p1 * p1 + EPS_K);
#pragma unroll
                for (int k = 0; k < VPT; ++k) {
                    const float s = fsin_rev((xi - yv[k]) * inv2p);
                    tmp[k] = p0sq * fexp2(s * s * c2);
                }
            }

            switch (ptr) {
                case 0:
#pragma unroll
                    for (int k = 0; k < VPT; ++k) s0[k] = tmp[k];
                    break;
                case 1:
#pragma unroll
                    for (int k = 0; k < VPT; ++k) s1[k] = tmp[k];
                    break;
                case 2:
#pragma unroll
                    for (int k = 0; k < VPT; ++k) s2[k] = tmp[k];
                    break;
                default:
#pragma unroll
                    for (int k = 0; k < VPT; ++k) s3[k] = tmp[k];
                    break;
            }
            ptr += 1;
        }
    }

    float4 o0 = make_float4(s0[0], s0[1], s0[2], s0[3]);
    float4 o1 = make_float4(s0[4], s0[5], s0[6], s0[7]);
    float4* o4 = reinterpret_cast<float4*>(out + (size_t)i * d2 + jb);
    o4[0] = o0;
    o4[1] = o1;
}

extern "C" void kernel_launch(void* const* d_in, const int* in_sizes, int n_in,
                              void* d_out, int out_size, void* d_ws, size_t ws_size,
                              hipStream_t stream) {
    const float* x      = (const float*)d_in[0];
    const float* y      = (const float*)d_in[1];
    const int*   expr   = (const int*)d_in[2];
    const int*   lvl    = (const int*)d_in[3];
    const float* params = (const float*)d_in[5];
    float*       out    = (float*)d_out;

    const int d1 = in_sizes[0];
    const int d2 = in_sizes[1];

    dim3 grid(d1);
    dim3 block(d2 / VPT);   // 2048/8 = 256
    tree_eval_kernel<<<grid, block, 0, stream>>>(x, y, expr, lvl, params, out, d2);
}